// Round 10
// baseline (335.377 us; speedup 1.0000x reference)
//
#include <hip/hip_runtime.h>

// ---------------- common helpers ----------------
typedef __attribute__((ext_vector_type(8))) short short8;
typedef __attribute__((ext_vector_type(4))) float f32x4;

__device__ __forceinline__ unsigned short f2b(float f) {
    union { float f; unsigned u; } uf; uf.f = f;
    unsigned r = uf.u + 0x7fffu + ((uf.u >> 16) & 1u);   // RNE, finite inputs
    return (unsigned short)(r >> 16);
}
__device__ __forceinline__ float b2f(unsigned short b) {
    union { unsigned u; float f; } uf; uf.u = ((unsigned)b) << 16;
    return uf.f;
}
__device__ __forceinline__ void gload_lds16(const void* g, void* l) {
    __builtin_amdgcn_global_load_lds(
        (const __attribute__((address_space(1))) void*)g,
        (__attribute__((address_space(3))) void*)l,
        16, 0, 0);
}

#define B_SZ 4096
#define F_ST 20
#define F_DY 10
#define MLEN 50
#define E_SZ 16
#define F_ALL 30
#define NPAIR 435
#define DIN 6960
#define KP 7168            /* DIN zero-padded; 4 k-slices of 1792 (28 BK=64 steps) */
#define H_SZ 512
#define BN_EPS 1e-5f

// --- k_dyemb: dynamic masked-mean + dy_lr; one wave per (b,f) ---------------
// e==0 lanes (l in {0,16,32,48}) also gather dy_lr[id] on the same broadcast
// id stream; wave-reduce -> one atomicAdd(lr_sc[b]) per wave.  Absorbs the
// dynamic half of the old k_lr (saves its 8.2 MB dy_ids re-read + dispatch).
__global__ __launch_bounds__(512) void k_dyemb(
    const int* __restrict__ dy_ids, const int* __restrict__ dy_len,
    const float* __restrict__ dy_emb, const float* __restrict__ dy_lr,
    float* __restrict__ all_emb, float* __restrict__ lr_sc)
{
    int gw = blockIdx.x * 8 + (threadIdx.x >> 6);   // wave id = b*F_DY + f
    int l = threadIdx.x & 63;
    int b = gw / F_DY, f = gw - b * F_DY;
    int len = dy_len[b * F_DY + f]; if (len < 1) len = 1;   // wave-uniform
    const int* ids = dy_ids + ((long)b * F_DY + f) * MLEN;
    int idv = (l < MLEN) ? ids[l] : 0;              // coalesced, one load/lane
    int e = l & 15, mq = l >> 4;
    float acc = 0.f, lac = 0.f;
#pragma unroll
    for (int j = 0; j < 13; ++j) {                  // 13*4 >= MLEN
        int m = mq + (j << 2);                      // m <= 51 < 64
        int id = __shfl(idv, m, 64);                // all 64 lanes active
        bool p = (m < len);
        float v = p ? dy_emb[(long)id * E_SZ + e] : 0.f;
        acc += v;
        if (e == 0) lac += p ? dy_lr[id] : 0.f;
    }
    acc += __shfl_xor(acc, 16, 64);
    acc += __shfl_xor(acc, 32, 64);
    lac += __shfl_xor(lac, 16, 64);
    lac += __shfl_xor(lac, 32, 64);
    if (l == 0) atomicAdd(&lr_sc[b], lac);
    if (l < 16)
        all_emb[((long)b * F_ALL + F_ST + f) * E_SZ + e] = acc / (float)len;
}

// ---- k_x: static gather + pairwise products -> x16 + BN1 stats + st_lr -----
// v4: absorbs k_stemb (static embeddings gathered straight into LDS; the
// 10.5 MB static all_emb HBM round-trip disappears) and k_lr's static part
// (st_lr summed into LDS, + bias -> lr_sc).  Phase C (products/stats) is
// v3's verbatim lane-consecutive pattern, 1024 threads, 7 d-slices.
__global__ __launch_bounds__(1024) void k_x(
    const int* __restrict__ st_ids, const float* __restrict__ st_emb,
    const float* __restrict__ st_lr, const float* __restrict__ bias,
    const float* __restrict__ all_emb, unsigned short* __restrict__ x16,
    float* __restrict__ s1, float* __restrict__ s1q,
    float* __restrict__ lr_sc)
{
    __shared__ float es[16 * 480];
    __shared__ int pip[NPAIR], pjp[NPAIR];
    __shared__ float lrs[16];
    int t = threadIdx.x, b0 = blockIdx.x * 16;
    if (t < 16) lrs[t] = 0.f;
    if (t < NPAIR) {
        int i = 0, rem = t;
        while (rem >= (F_ALL - 1) - i) { rem -= (F_ALL - 1) - i; ++i; }
        pip[t] = i; pjp[t] = i + 1 + rem;
    }
    __syncthreads();

    // phase A: static embeddings -> es (1280 f32x4 units) + st_lr sums
    for (int i = t; i < 16 * F_ST * 4; i += 1024) {
        int e4 = i & 3, bf = i >> 2;
        int r = bf / F_ST, f = bf - r * F_ST;
        int id = st_ids[(b0 + r) * F_ST + f];
        f32x4 v = *(const f32x4*)(st_emb + (long)id * E_SZ + e4 * 4);
        *(f32x4*)(&es[r * 480 + f * 16 + e4 * 4]) = v;
        if (e4 == 0) atomicAdd(&lrs[r], st_lr[id]);
    }
    // phase A2: dynamic half from all_emb (written by k_dyemb)
    for (int i = t; i < 16 * 160; i += 1024) {
        int r = i / 160, j = i - r * 160;
        es[r * 480 + 320 + j] = all_emb[((long)(b0 + r) * 480) + 320 + j];
    }
    __syncthreads();
    if (t < 16) atomicAdd(&lr_sc[b0 + t], lrs[t] + bias[0]);

    // phase C: products -> x16 (bf16) + BN1 stats (v3 verbatim)
    int ci[7], cj[7];
#pragma unroll
    for (int k = 0; k < 7; ++k) {
        int d = t + (k << 10);
        if (d < DIN) {
            int p = d >> 4, e = d & 15;
            ci[k] = pip[p] * E_SZ + e;
            cj[k] = pjp[p] * E_SZ + e;
        } else { ci[k] = -1; cj[k] = 0; }
    }
    float sum[7], sq[7];
#pragma unroll
    for (int k = 0; k < 7; ++k) { sum[k] = 0.f; sq[k] = 0.f; }

    for (int r = 0; r < 16; ++r) {
        const float* row = &es[r * 480];
        long ob = (long)(b0 + r) * KP;
#pragma unroll
        for (int k = 0; k < 7; ++k) {
            int d = t + (k << 10);
            if (ci[k] >= 0) {
                float v = row[ci[k]] * row[cj[k]];
                unsigned short h = f2b(v);
                x16[ob + d] = h;
                float vb = b2f(h);
                sum[k] += vb; sq[k] += vb * vb;
            } else if (d < KP) {
                x16[ob + d] = 0;           // K padding
            }
        }
    }
#pragma unroll
    for (int k = 0; k < 7; ++k) {
        int d = t + (k << 10);
        if (ci[k] >= 0) { atomicAdd(&s1[d], sum[k]); atomicAdd(&s1q[d], sq[k]); }
    }
}

// ============ k_prep: BN1 fold (blocks 0..27) + W3 row-sums (28..59) ========
__global__ __launch_bounds__(256) void k_prep(
    const float* __restrict__ s, const float* __restrict__ sqs,
    const float* __restrict__ g, const float* __restrict__ bb,
    float* __restrict__ a, float* __restrict__ c,
    const float* __restrict__ W3, float* __restrict__ w3s)
{
    int t = threadIdx.x;
    if (blockIdx.x < 28) {
        int d = blockIdx.x * 256 + t;
        if (d < DIN) {
            float m = s[d] * (1.f / 4096.f);
            float var = sqs[d] * (1.f / 4096.f) - m * m;
            float av = g[d] * rsqrtf(var + BN_EPS);
            a[d] = av; c[d] = bb[d] - m * av;
        }
    } else {
        int row = (blockIdx.x - 28) * 16 + (t >> 4), sub = t & 15;
        float acc = 0.f;
        for (int i = 0; i < 32; ++i) acc += W3[(long)row * H_SZ + sub + i * 16];
#pragma unroll
        for (int sh = 8; sh; sh >>= 1) acc += __shfl_xor(acc, sh, 16);
        if (sub == 0) w3s[row] = acc;
    }
}

// ---------------- W1^T cast + const1 fold (w1t[n][k] = a1[k]*W1[k][n]) --------
__global__ __launch_bounds__(256) void k_w1t(
    const float* __restrict__ W1, const float* __restrict__ a1,
    const float* __restrict__ c1, unsigned short* __restrict__ w1t,
    float* __restrict__ con)
{
    int gi = blockIdx.x * 256 + threadIdx.x;   // 896*512 groups
    int kg = gi >> 9, n = gi & 511;
    short8 out; float cacc = 0.f;
#pragma unroll
    for (int i = 0; i < 8; ++i) {
        int k = kg * 8 + i;
        if (k < DIN) {
            float w = W1[(long)k * H_SZ + n];
            out[i] = (short)f2b(a1[k] * w);
            cacc += c1[k] * w;
        } else out[i] = 0;
    }
    *(short8*)(w1t + (long)n * KP + kg * 8) = out;
    atomicAdd(&con[n], cacc);
}

// ======== k_gemm1 core: split-K bf16 MFMA, swizzled LDS ====================
// tile M=64 x N=256, z=4 K-slices of 1792 (28 BK=64 steps).  Grid 512 =
// 64 m x (2 n x 4 z).  s&7 -> (n,z) combo: one per XCD (L2-resident B slice).
// PS: plain stores to per-z partial buffers; AT: atomic fallback.
template <int PS>
__device__ __forceinline__ void gemm1_body(
    const unsigned short* __restrict__ A, const unsigned short* __restrict__ Bt,
    float* __restrict__ p0, float* __restrict__ p1,
    float* __restrict__ p2, float* __restrict__ p3)
{
    __shared__ __align__(16) short As[64 * 64];    // 8 KB
    __shared__ __align__(16) short Bs[256 * 64];   // 32 KB
    const int t = threadIdx.x;
    const int w = t >> 6, l = t & 63;
    const int lm = l & 15, lq = l >> 4;
    const int s = blockIdx.x;                      // dispatch slot
    const int combo = s & 7;                       // one (n,z) per XCD
    const int nb = combo & 1;                      // n-half
    const int z = combo >> 1;                      // k-quarter
    const int row0 = (s >> 3) * 64;                // m-tile
    const int k0 = z * (KP / 4);                   // 1792-wide K slice
    const int col_base = nb * 256;

    const int srow = t >> 3;                       // staging row (0..63)
    const int gch = (t & 7) ^ (srow & 7);          // xor-permuted source chunk
    const unsigned short* gA = A + (long)(row0 + srow) * KP + k0 + gch * 8;
    const unsigned short* gB = Bt + (long)(col_base + srow) * KP + k0 + gch * 8;
    short* AsW = As + w * 512;                     // wave-contiguous dest
    short* BsW = Bs + w * 512;

    f32x4 acc[4][2];
#pragma unroll
    for (int mi = 0; mi < 4; ++mi)
#pragma unroll
        for (int ni = 0; ni < 2; ++ni) acc[mi][ni] = (f32x4){0.f,0.f,0.f,0.f};

    for (int kt = 0; kt < 28; ++kt) {
        gload_lds16(gA, AsW);                       // A: 64 rows x 64 k
#pragma unroll
        for (int c = 0; c < 4; ++c)                 // B: 256 rows x 64 k
            gload_lds16(gB + (long)(64 * c) * KP, BsW + c * 4096);
        __syncthreads();
#pragma unroll
        for (int sb = 0; sb < 2; ++sb) {            // two 32-wide k sub-blocks
            short8 af[4];
#pragma unroll
            for (int mi = 0; mi < 4; ++mi) {
                int m = mi * 16 + lm;
                int sl = (sb * 4 + lq) ^ (m & 7);
                af[mi] = *(const short8*)(As + m * 64 + sl * 8);
            }
#pragma unroll
            for (int ni = 0; ni < 2; ++ni) {
                int rb = w * 32 + ni * 16 + lm;     // LDS B row (0..255)
                int sl = (sb * 4 + lq) ^ (rb & 7);
                short8 bf = *(const short8*)(Bs + rb * 64 + sl * 8);
#pragma unroll
                for (int mi = 0; mi < 4; ++mi)
                    acc[mi][ni] = __builtin_amdgcn_mfma_f32_16x16x32_bf16(
                        af[mi], bf, acc[mi][ni], 0, 0, 0);
            }
        }
        __syncthreads();
        gA += 64; gB += 64;
    }

    // C/D layout: col = lane&15 (n), row = (lane>>4)*4 + reg (m)
    float* pz;
    if (PS) pz = (z == 0) ? p0 : (z == 1) ? p1 : (z == 2) ? p2 : p3;
    else    pz = p0;
#pragma unroll
    for (int ni = 0; ni < 2; ++ni) {
        int col = col_base + w * 32 + ni * 16 + lm;
#pragma unroll
        for (int mi = 0; mi < 4; ++mi) {
            int rbase = row0 + mi * 16 + lq * 4;
#pragma unroll
            for (int r = 0; r < 4; ++r) {
                long idx = (long)(rbase + r) * H_SZ + col;
                if (PS) pz[idx] = acc[mi][ni][r];
                else    atomicAdd(&pz[idx], acc[mi][ni][r]);
            }
        }
    }
}

__global__ __launch_bounds__(512, 4) void k_gemm1_ps(
    const unsigned short* __restrict__ A, const unsigned short* __restrict__ Bt,
    float* __restrict__ p0, float* __restrict__ p1,
    float* __restrict__ p2, float* __restrict__ p3)
{ gemm1_body<1>(A, Bt, p0, p1, p2, p3); }

__global__ __launch_bounds__(512, 4) void k_gemm1_at(
    const unsigned short* __restrict__ A, const unsigned short* __restrict__ Bt,
    float* __restrict__ accbuf)
{ gemm1_body<0>(A, Bt, accbuf, accbuf, accbuf, accbuf); }

// ============ k_ep: partials -> relu(.+con1+b1) bf16 r1, + BN2 stats ========
template <int PS>
__device__ __forceinline__ void ep_body(
    const float* __restrict__ p0, const float* __restrict__ p1,
    const float* __restrict__ p2, const float* __restrict__ p3,
    const float* __restrict__ con1, const float* __restrict__ b1,
    unsigned short* __restrict__ r1, float* __restrict__ s2,
    float* __restrict__ s2q)
{
    __shared__ float con[H_SZ];
    int t = threadIdx.x, r0 = blockIdx.x * 32;
    con[t] = b1[t] + con1[t];
    con[t + 256] = b1[t + 256] + con1[t + 256];
    __syncthreads();
    float a0 = 0.f, q0 = 0.f, a1v = 0.f, q1 = 0.f;
    for (int r = 0; r < 32; ++r) {
        long base = (long)(r0 + r) * H_SZ;
        float v0, v1;
        if (PS) {
            v0 = p0[base + t] + p1[base + t] + p2[base + t] + p3[base + t]
               + con[t];
            v1 = p0[base + t + 256] + p1[base + t + 256]
               + p2[base + t + 256] + p3[base + t + 256] + con[t + 256];
        } else {
            v0 = p0[base + t] + con[t];
            v1 = p0[base + t + 256] + con[t + 256];
        }
        v0 = v0 > 0.f ? v0 : 0.f;
        v1 = v1 > 0.f ? v1 : 0.f;
        unsigned short h0 = f2b(v0), h1 = f2b(v1);
        r1[base + t] = h0; r1[base + t + 256] = h1;
        float b0 = b2f(h0), b1f = b2f(h1);
        a0 += b0; q0 += b0 * b0; a1v += b1f; q1 += b1f * b1f;
    }
    atomicAdd(&s2[t], a0);        atomicAdd(&s2q[t], q0);
    atomicAdd(&s2[t + 256], a1v); atomicAdd(&s2q[t + 256], q1);
}

__global__ __launch_bounds__(256) void k_ep_ps(
    const float* __restrict__ p0, const float* __restrict__ p1,
    const float* __restrict__ p2, const float* __restrict__ p3,
    const float* __restrict__ con1, const float* __restrict__ b1,
    unsigned short* __restrict__ r1, float* __restrict__ s2,
    float* __restrict__ s2q)
{ ep_body<1>(p0, p1, p2, p3, con1, b1, r1, s2, s2q); }

__global__ __launch_bounds__(256) void k_ep_at(
    const float* __restrict__ accbuf,
    const float* __restrict__ con1, const float* __restrict__ b1,
    unsigned short* __restrict__ r1, float* __restrict__ s2,
    float* __restrict__ s2q)
{ ep_body<0>(accbuf, accbuf, accbuf, accbuf, con1, b1, r1, s2, s2q); }

// ============ k_w2t: inline BN2 fold + W2^T bf16 cast + con2 ================
__global__ __launch_bounds__(256) void k_w2t(
    const float* __restrict__ W2, const float* __restrict__ s2,
    const float* __restrict__ s2q, const float* __restrict__ g2,
    const float* __restrict__ bb2, unsigned short* __restrict__ w2t,
    float* __restrict__ con)
{
    int gi = blockIdx.x * 256 + threadIdx.x;   // 64 kg * 512 n
    int kg = gi >> 9, n = gi & 511;
    short8 out; float cacc = 0.f;
#pragma unroll
    for (int i = 0; i < 8; ++i) {
        int k = kg * 8 + i;
        float m = s2[k] * (1.f / 4096.f);
        float var = s2q[k] * (1.f / 4096.f) - m * m;
        float av = g2[k] * rsqrtf(var + BN_EPS);
        float cv = bb2[k] - m * av;
        float w = W2[(long)k * H_SZ + n];
        out[i] = (short)f2b(av * w);
        cacc += cv * w;
    }
    *(short8*)(w2t + (long)n * H_SZ + kg * 8) = out;
    atomicAdd(&con[n], cacc);
}

// ====== k_gemm2: full-K bf16 MFMA, 2-phase dbuf, fused relu + col stats =====
__global__ __launch_bounds__(512) void k_gemm2(
    const unsigned short* __restrict__ A, const unsigned short* __restrict__ Bt,
    const float* __restrict__ cvec, const float* __restrict__ bvec,
    unsigned short* __restrict__ Out, float* __restrict__ ss,
    float* __restrict__ sq)
{
    const int Kp = H_SZ;
    __shared__ __align__(16) short As[2][128 * 32];   // 2 x 8 KB
    __shared__ __align__(16) short Bs[2][64 * 32];    // 2 x 4 KB
    const int t = threadIdx.x;
    const int w = t >> 6, l = t & 63;
    const int wm = w >> 1, wn = w & 1;
    const int lm = l & 15, lq = l >> 4;
    const int row0 = blockIdx.y * 128;
    const int col0 = blockIdx.x * 64;

    const unsigned short* gA = A + (long)(row0 + (t >> 2)) * Kp + ((t & 3) * 8);
    const unsigned short* gB = Bt + (long)(col0 + ((t >> 2) & 63)) * Kp + ((t & 3) * 8);

#define STAGE2(kt, pb) do {                                                   \
        gload_lds16(gA + (kt) * 32, &As[pb][w * 512]);                        \
        if (t < 256) gload_lds16(gB + (kt) * 32, &Bs[pb][w * 512]);           \
    } while (0)

    f32x4 acc00 = {0.f,0.f,0.f,0.f}, acc01 = acc00, acc10 = acc00, acc11 = acc00;

    STAGE2(0, 0);
    __syncthreads();

    for (int kt = 0; kt < Kp / 32; ++kt) {
        const int pb = kt & 1;
        if (kt < Kp / 32 - 1) STAGE2(kt + 1, pb ^ 1);   // prefetch FIRST
        const short* aBase0 = &As[pb][(wm * 32 + lm) * 32 + lq * 8];
        const short* bBase0 = &Bs[pb][(wn * 32 + lm) * 32 + lq * 8];
        short8 af0 = *(const short8*)aBase0;
        short8 af1 = *(const short8*)(aBase0 + 16 * 32);
        short8 bf0 = *(const short8*)bBase0;
        short8 bf1 = *(const short8*)(bBase0 + 16 * 32);
        acc00 = __builtin_amdgcn_mfma_f32_16x16x32_bf16(af0, bf0, acc00, 0, 0, 0);
        acc01 = __builtin_amdgcn_mfma_f32_16x16x32_bf16(af0, bf1, acc01, 0, 0, 0);
        acc10 = __builtin_amdgcn_mfma_f32_16x16x32_bf16(af1, bf0, acc10, 0, 0, 0);
        acc11 = __builtin_amdgcn_mfma_f32_16x16x32_bf16(af1, bf1, acc11, 0, 0, 0);
        __syncthreads();
    }
#undef STAGE2

    f32x4 accs[2][2] = {{acc00, acc01}, {acc10, acc11}};
#pragma unroll
    for (int ni = 0; ni < 2; ++ni) {
        int col = col0 + wn * 32 + ni * 16 + lm;
        float cb = cvec[col] + bvec[col];
        float psum = 0.f, psq = 0.f;
#pragma unroll
        for (int mi = 0; mi < 2; ++mi) {
            int rbase = row0 + wm * 32 + mi * 16 + lq * 4;
#pragma unroll
            for (int r = 0; r < 4; ++r) {
                float v = accs[mi][ni][r] + cb;
                v = v > 0.f ? v : 0.f;
                unsigned short h = f2b(v);
                Out[(long)(rbase + r) * H_SZ + col] = h;
                float vb = b2f(h);
                psum += vb; psq += vb * vb;
            }
        }
        psum += __shfl_xor(psum, 16, 64); psum += __shfl_xor(psum, 32, 64);
        psq  += __shfl_xor(psq , 16, 64); psq  += __shfl_xor(psq , 32, 64);
        if (lq == 0) { atomicAdd(&ss[col], psum); atomicAdd(&sq[col], psq); }
    }
}

// ============ k_final: inline BN3 fold + GEMV + lr ==========================
__global__ __launch_bounds__(256) void k_final(
    const unsigned short* __restrict__ r2, const float* __restrict__ s3,
    const float* __restrict__ s3q, const float* __restrict__ g3,
    const float* __restrict__ bb3, const float* __restrict__ w3s,
    const float* __restrict__ b3, const float* __restrict__ lr_score,
    float* __restrict__ out)
{
    int t = threadIdx.x, w = t >> 6, l = t & 63;
    int b = blockIdx.x * 4 + w;
    float acc = 0.f;
#pragma unroll
    for (int i = 0; i < 8; ++i) {
        int e = i * 64 + l;
        float m = s3[e] * (1.f / 4096.f);
        float var = s3q[e] * (1.f / 4096.f) - m * m;
        float a3 = g3[e] * rsqrtf(var + BN_EPS);
        float c3 = bb3[e] - m * a3;
        float v = a3 * b2f(r2[(long)b * H_SZ + e]) + c3;
        acc += v * w3s[e] + b3[e];
    }
    for (int s = 32; s; s >>= 1) acc += __shfl_down(acc, s, 64);
    if (l == 0) out[b] = lr_score[b] + acc;
}

// ---------------- launcher ----------------
extern "C" void kernel_launch(void* const* d_in, const int* in_sizes, int n_in,
                              void* d_out, int out_size, void* d_ws, size_t ws_size,
                              hipStream_t stream) {
    const int*   st_ids = (const int*)d_in[0];
    const int*   dy_ids = (const int*)d_in[1];
    const int*   dy_len = (const int*)d_in[2];
    const float* st_emb = (const float*)d_in[3];
    const float* dy_emb = (const float*)d_in[4];
    const float* st_lr  = (const float*)d_in[5];
    const float* dy_lr  = (const float*)d_in[6];
    const float* bias   = (const float*)d_in[7];
    const float* bn1_g  = (const float*)d_in[8];
    const float* bn1_b  = (const float*)d_in[9];
    const float* W1     = (const float*)d_in[10];
    const float* b1     = (const float*)d_in[11];
    const float* bn2_g  = (const float*)d_in[12];
    const float* bn2_b  = (const float*)d_in[13];
    const float* W2     = (const float*)d_in[14];
    const float* b2     = (const float*)d_in[15];
    const float* bn3_g  = (const float*)d_in[16];
    const float* bn3_b  = (const float*)d_in[17];
    const float* W3     = (const float*)d_in[18];
    const float* b3     = (const float*)d_in[19];
    // d_in[20..23] feed only the dead final layer — skipped.

    char* ws = (char*)d_ws;
    size_t off = 0;
    auto alloc = [&](size_t bytes) -> char* {
        char* p = ws + off;
        off = (off + bytes + 255) & ~(size_t)255;
        return p;
    };
    // Union region R (8.39 MB), time-multiplexed:
    //   phase 1: all_emb (dyn half)     [k_dyemb -> k_x]
    //   phase 2: accbuf / partial z=0   [k_gemm1 -> k_ep]
    //   phase 3: r2      (4.19 MB)      [k_gemm2 -> k_final]
    char* R = alloc((size_t)B_SZ * H_SZ * 4);      // 8,388,608 B
    float*          all_emb = (float*)R;
    float*          accbuf  = (float*)R;           // = partial z=0 in PS mode
    unsigned short* r2      = (unsigned short*)R;

    unsigned short* x16     = (unsigned short*)alloc((size_t)B_SZ * KP * 2);
    unsigned short* w1t     = (unsigned short*)alloc((size_t)H_SZ * KP * 2);
    unsigned short* r1      = (unsigned short*)alloc((size_t)B_SZ * H_SZ * 2);
    unsigned short* w2t     = (unsigned short*)alloc((size_t)H_SZ * H_SZ * 2);
    float* a1  = (float*)alloc(KP * 4);
    float* c1  = (float*)alloc(KP * 4);
    float* w3s = (float*)alloc(H_SZ * 4);
    char* zstart = ws + off;                       // ---- zeroed stats ----
    float* s1   = (float*)alloc(KP * 4);
    float* s1q  = (float*)alloc(KP * 4);
    float* con1 = (float*)alloc(H_SZ * 4);
    float* s2   = (float*)alloc(H_SZ * 4);
    float* s2q  = (float*)alloc(H_SZ * 4);
    float* con2 = (float*)alloc(H_SZ * 4);
    float* s3   = (float*)alloc(H_SZ * 4);
    float* s3q  = (float*)alloc(H_SZ * 4);
    float* lr_sc = (float*)alloc(B_SZ * 4);        // zeroed: receives atomics
    size_t zbytes = (size_t)((ws + off) - zstart);
    // base layout ≈ 79.3 MB (< 81.2 MB proven safe)

    // Optional split-K partial buffers (z=1..3); z=0 reuses R.  Only used if
    // the workspace is big enough — otherwise fall back to atomic path.
    float* pb1 = (float*)alloc((size_t)B_SZ * H_SZ * 4);
    float* pb2 = (float*)alloc((size_t)B_SZ * H_SZ * 4);
    float* pb3 = (float*)alloc((size_t)B_SZ * H_SZ * 4);
    const bool ps = (off <= ws_size);              // ~104.5 MB needed

    hipMemsetAsync(zstart, 0, zbytes, stream);
    k_dyemb<<<(B_SZ * F_DY) / 8, 512, 0, stream>>>(dy_ids, dy_len, dy_emb,
                                                   dy_lr, all_emb, lr_sc);
    k_x<<<B_SZ / 16, 1024, 0, stream>>>(st_ids, st_emb, st_lr, bias,
                                        all_emb, x16, s1, s1q, lr_sc);
    k_prep<<<60, 256, 0, stream>>>(s1, s1q, bn1_g, bn1_b, a1, c1, W3, w3s);
    k_w1t<<<(896 * 512) / 256, 256, 0, stream>>>(W1, a1, c1, w1t, con1);
    if (ps) {
        // all_emb dead; R = partial z=0 (fully overwritten, no memset needed)
        k_gemm1_ps<<<512, 512, 0, stream>>>(x16, w1t, accbuf, pb1, pb2, pb3);
        k_ep_ps<<<128, 256, 0, stream>>>(accbuf, pb1, pb2, pb3, con1, b1,
                                         r1, s2, s2q);
    } else {
        hipMemsetAsync(R, 0, (size_t)B_SZ * H_SZ * 4, stream);
        k_gemm1_at<<<512, 512, 0, stream>>>(x16, w1t, accbuf);
        k_ep_at<<<128, 256, 0, stream>>>(accbuf, con1, b1, r1, s2, s2q);
    }
    k_w2t<<<128, 256, 0, stream>>>(W2, s2, s2q, bn2_g, bn2_b, w2t, con2);
    // accbuf dead; repurpose R as r2
    k_gemm2<<<dim3(8, 32), 512, 0, stream>>>(r1, w2t, con2, b2, r2, s3, s3q);
    k_final<<<B_SZ / 4, 256, 0, stream>>>(r2, s3, s3q, bn3_g, bn3_b, w3s, b3,
                                          lr_sc, (float*)d_out);
}

// Round 11
// 324.150 us; speedup vs baseline: 1.0346x; 1.0346x over previous
//
#include <hip/hip_runtime.h>

// ---------------- common helpers ----------------
typedef __attribute__((ext_vector_type(8))) short short8;
typedef __attribute__((ext_vector_type(4))) float f32x4;

__device__ __forceinline__ unsigned short f2b(float f) {
    union { float f; unsigned u; } uf; uf.f = f;
    unsigned r = uf.u + 0x7fffu + ((uf.u >> 16) & 1u);   // RNE, finite inputs
    return (unsigned short)(r >> 16);
}
__device__ __forceinline__ float b2f(unsigned short b) {
    union { unsigned u; float f; } uf; uf.u = ((unsigned)b) << 16;
    return uf.f;
}
__device__ __forceinline__ void gload_lds16(const void* g, void* l) {
    __builtin_amdgcn_global_load_lds(
        (const __attribute__((address_space(1))) void*)g,
        (__attribute__((address_space(3))) void*)l,
        16, 0, 0);
}

#define B_SZ 4096
#define F_ST 20
#define F_DY 10
#define MLEN 50
#define E_SZ 16
#define F_ALL 30
#define NPAIR 435
#define DIN 6960
#define KP 7168            /* DIN zero-padded; 4 k-slices of 1792 (28 BK=64 steps) */
#define H_SZ 512
#define BN_EPS 1e-5f

// ---------------- static embedding gather (float4 per thread) ----------------
__global__ __launch_bounds__(256) void k_stemb(
    const int* __restrict__ st_ids, const float* __restrict__ st_emb,
    float* __restrict__ all_emb)
{
    int idx = blockIdx.x * 256 + threadIdx.x;    // (b*F_ST+f)*4 + e4
    int e4 = idx & 3, bf = idx >> 2;
    int b = bf / F_ST, f = bf % F_ST;
    int id = st_ids[bf];
    f32x4 v = *(const f32x4*)(st_emb + (long)id * E_SZ + e4 * 4);
    *(f32x4*)(all_emb + ((long)b * F_ALL + f) * E_SZ + e4 * 4) = v;
}

// ------- dynamic masked-mean: one wave per (b,f); ids broadcast via shfl -----
// v2: f32x4 gathers.  Lane covers (m-slot, e-quarter): e4=l&3, mq=l>>2 ->
// 16 m-slots/iteration, 4 iterations (was 13 scalar-load iterations).  Same
// bytes, 3x fewer VMEM issues.  Reduce across mq lanes (stride 4) via
// shfl_xor; 4 lanes write one 16B chunk each.
__global__ __launch_bounds__(512) void k_dyemb(
    const int* __restrict__ dy_ids, const int* __restrict__ dy_len,
    const float* __restrict__ dy_emb, float* __restrict__ all_emb)
{
    int gw = blockIdx.x * 8 + (threadIdx.x >> 6);   // wave id = b*F_DY + f
    int l = threadIdx.x & 63;
    int b = gw / F_DY, f = gw - b * F_DY;
    int len = dy_len[b * F_DY + f]; if (len < 1) len = 1;   // wave-uniform
    const int* ids = dy_ids + ((long)b * F_DY + f) * MLEN;
    int idv = (l < MLEN) ? ids[l] : 0;              // coalesced, one load/lane
    int e4 = l & 3, mq = l >> 2;                    // e-quarter, m-slot base
    f32x4 acc = (f32x4){0.f, 0.f, 0.f, 0.f};
#pragma unroll
    for (int j = 0; j < 4; ++j) {                   // 4*16 = 64 >= MLEN
        int m = mq + (j << 4);                      // m <= 63
        int id = __shfl(idv, m, 64);                // all 64 lanes active
        if (m < len)
            acc += *(const f32x4*)(dy_emb + (long)id * E_SZ + e4 * 4);
    }
#pragma unroll
    for (int sh = 4; sh <= 32; sh <<= 1) {          // reduce over mq lanes
        acc[0] += __shfl_xor(acc[0], sh, 64);
        acc[1] += __shfl_xor(acc[1], sh, 64);
        acc[2] += __shfl_xor(acc[2], sh, 64);
        acc[3] += __shfl_xor(acc[3], sh, 64);
    }
    if (l < 4) {
        float inv = 1.f / (float)len;
        f32x4 o = { acc[0] * inv, acc[1] * inv, acc[2] * inv, acc[3] * inv };
        *(f32x4*)(all_emb + ((long)b * F_ALL + F_ST + f) * E_SZ + l * 4) = o;
    }
}

// ---------------- linear (lr) terms: one wave per batch row ----------------
__global__ __launch_bounds__(512) void k_lr(
    const int* __restrict__ st_ids, const int* __restrict__ dy_ids,
    const int* __restrict__ dy_len, const float* __restrict__ st_lr,
    const float* __restrict__ dy_lr, const float* __restrict__ bias,
    float* __restrict__ lr_score)
{
    int w = threadIdx.x >> 6, l = threadIdx.x & 63;
    int b = blockIdx.x * 8 + w;
    float acc = 0.f;
    if (l < F_ST) acc += st_lr[st_ids[b * F_ST + l]];
#pragma unroll
    for (int i = 0; i < 8; ++i) {                   // 10 fields x 50 slots = 500
        int idx = i * 64 + l;
        if (idx < F_DY * MLEN) {
            int f = idx / MLEN, m = idx - f * MLEN;
            int len = dy_len[b * F_DY + f]; if (len < 1) len = 1;
            if (m < len)
                acc += dy_lr[dy_ids[((long)b * F_DY + f) * MLEN + m]];
        }
    }
    for (int s = 32; s; s >>= 1) acc += __shfl_down(acc, s, 64);
    if (l == 0) lr_score[b] = bias[0] + acc;
}

// ---------- k_x: pairwise products -> x (bf16, K-padded) + BN1 stats --------
// v3: v1's lane-consecutive access pattern, 1024-thread block (16 waves/CU).
__global__ __launch_bounds__(1024) void k_x(
    const float* __restrict__ all_emb, unsigned short* __restrict__ x16,
    float* __restrict__ s1, float* __restrict__ s1q)
{
    __shared__ float es[16 * 480];
    __shared__ int pip[NPAIR], pjp[NPAIR];
    int t = threadIdx.x, b0 = blockIdx.x * 16;
    if (t < NPAIR) {
        int i = 0, rem = t;
        while (rem >= (F_ALL - 1) - i) { rem -= (F_ALL - 1) - i; ++i; }
        pip[t] = i; pjp[t] = i + 1 + rem;
    }
    for (int idx = t; idx < 16 * 480; idx += 1024)
        es[idx] = all_emb[(long)b0 * 480 + idx];
    __syncthreads();

    int ci[7], cj[7];
#pragma unroll
    for (int k = 0; k < 7; ++k) {
        int d = t + (k << 10);
        if (d < DIN) {
            int p = d >> 4, e = d & 15;
            ci[k] = pip[p] * E_SZ + e;
            cj[k] = pjp[p] * E_SZ + e;
        } else { ci[k] = -1; cj[k] = 0; }
    }
    float sum[7], sq[7];
#pragma unroll
    for (int k = 0; k < 7; ++k) { sum[k] = 0.f; sq[k] = 0.f; }

    for (int r = 0; r < 16; ++r) {
        const float* row = &es[r * 480];
        long ob = (long)(b0 + r) * KP;
#pragma unroll
        for (int k = 0; k < 7; ++k) {
            int d = t + (k << 10);
            if (ci[k] >= 0) {
                float v = row[ci[k]] * row[cj[k]];
                unsigned short h = f2b(v);
                x16[ob + d] = h;
                float vb = b2f(h);
                sum[k] += vb; sq[k] += vb * vb;
            } else if (d < KP) {
                x16[ob + d] = 0;           // K padding
            }
        }
    }
#pragma unroll
    for (int k = 0; k < 7; ++k) {
        int d = t + (k << 10);
        if (ci[k] >= 0) { atomicAdd(&s1[d], sum[k]); atomicAdd(&s1q[d], sq[k]); }
    }
}

// ============ k_prep: BN1 fold (blocks 0..27) + W3 row-sums (28..59) ========
__global__ __launch_bounds__(256) void k_prep(
    const float* __restrict__ s, const float* __restrict__ sqs,
    const float* __restrict__ g, const float* __restrict__ bb,
    float* __restrict__ a, float* __restrict__ c,
    const float* __restrict__ W3, float* __restrict__ w3s)
{
    int t = threadIdx.x;
    if (blockIdx.x < 28) {
        int d = blockIdx.x * 256 + t;
        if (d < DIN) {
            float m = s[d] * (1.f / 4096.f);
            float var = sqs[d] * (1.f / 4096.f) - m * m;
            float av = g[d] * rsqrtf(var + BN_EPS);
            a[d] = av; c[d] = bb[d] - m * av;
        }
    } else {
        int row = (blockIdx.x - 28) * 16 + (t >> 4), sub = t & 15;
        float acc = 0.f;
        for (int i = 0; i < 32; ++i) acc += W3[(long)row * H_SZ + sub + i * 16];
#pragma unroll
        for (int sh = 8; sh; sh >>= 1) acc += __shfl_xor(acc, sh, 16);
        if (sub == 0) w3s[row] = acc;
    }
}

// ---------------- W1^T cast + const1 fold (w1t[n][k] = a1[k]*W1[k][n]) --------
__global__ __launch_bounds__(256) void k_w1t(
    const float* __restrict__ W1, const float* __restrict__ a1,
    const float* __restrict__ c1, unsigned short* __restrict__ w1t,
    float* __restrict__ con)
{
    int gi = blockIdx.x * 256 + threadIdx.x;   // 896*512 groups
    int kg = gi >> 9, n = gi & 511;
    short8 out; float cacc = 0.f;
#pragma unroll
    for (int i = 0; i < 8; ++i) {
        int k = kg * 8 + i;
        if (k < DIN) {
            float w = W1[(long)k * H_SZ + n];
            out[i] = (short)f2b(a1[k] * w);
            cacc += c1[k] * w;
        } else out[i] = 0;
    }
    *(short8*)(w1t + (long)n * KP + kg * 8) = out;
    atomicAdd(&con[n], cacc);
}

// ======== k_gemm1 core: split-K bf16 MFMA, swizzled LDS ====================
// tile M=64 x N=256, z=4 K-slices of 1792 (28 BK=64 steps).  Grid 512 =
// 64 m x (2 n x 4 z).  s&7 -> (n,z) combo: one per XCD (L2-resident B slice).
// PS: plain stores to per-z partial buffers; AT: atomic fallback.
template <int PS>
__device__ __forceinline__ void gemm1_body(
    const unsigned short* __restrict__ A, const unsigned short* __restrict__ Bt,
    float* __restrict__ p0, float* __restrict__ p1,
    float* __restrict__ p2, float* __restrict__ p3)
{
    __shared__ __align__(16) short As[64 * 64];    // 8 KB
    __shared__ __align__(16) short Bs[256 * 64];   // 32 KB
    const int t = threadIdx.x;
    const int w = t >> 6, l = t & 63;
    const int lm = l & 15, lq = l >> 4;
    const int s = blockIdx.x;                      // dispatch slot
    const int combo = s & 7;                       // one (n,z) per XCD
    const int nb = combo & 1;                      // n-half
    const int z = combo >> 1;                      // k-quarter
    const int row0 = (s >> 3) * 64;                // m-tile
    const int k0 = z * (KP / 4);                   // 1792-wide K slice
    const int col_base = nb * 256;

    const int srow = t >> 3;                       // staging row (0..63)
    const int gch = (t & 7) ^ (srow & 7);          // xor-permuted source chunk
    const unsigned short* gA = A + (long)(row0 + srow) * KP + k0 + gch * 8;
    const unsigned short* gB = Bt + (long)(col_base + srow) * KP + k0 + gch * 8;
    short* AsW = As + w * 512;                     // wave-contiguous dest
    short* BsW = Bs + w * 512;

    f32x4 acc[4][2];
#pragma unroll
    for (int mi = 0; mi < 4; ++mi)
#pragma unroll
        for (int ni = 0; ni < 2; ++ni) acc[mi][ni] = (f32x4){0.f,0.f,0.f,0.f};

    for (int kt = 0; kt < 28; ++kt) {
        gload_lds16(gA, AsW);                       // A: 64 rows x 64 k
#pragma unroll
        for (int c = 0; c < 4; ++c)                 // B: 256 rows x 64 k
            gload_lds16(gB + (long)(64 * c) * KP, BsW + c * 4096);
        __syncthreads();
#pragma unroll
        for (int sb = 0; sb < 2; ++sb) {            // two 32-wide k sub-blocks
            short8 af[4];
#pragma unroll
            for (int mi = 0; mi < 4; ++mi) {
                int m = mi * 16 + lm;
                int sl = (sb * 4 + lq) ^ (m & 7);
                af[mi] = *(const short8*)(As + m * 64 + sl * 8);
            }
#pragma unroll
            for (int ni = 0; ni < 2; ++ni) {
                int rb = w * 32 + ni * 16 + lm;     // LDS B row (0..255)
                int sl = (sb * 4 + lq) ^ (rb & 7);
                short8 bf = *(const short8*)(Bs + rb * 64 + sl * 8);
#pragma unroll
                for (int mi = 0; mi < 4; ++mi)
                    acc[mi][ni] = __builtin_amdgcn_mfma_f32_16x16x32_bf16(
                        af[mi], bf, acc[mi][ni], 0, 0, 0);
            }
        }
        __syncthreads();
        gA += 64; gB += 64;
    }

    // C/D layout: col = lane&15 (n), row = (lane>>4)*4 + reg (m)
    float* pz;
    if (PS) pz = (z == 0) ? p0 : (z == 1) ? p1 : (z == 2) ? p2 : p3;
    else    pz = p0;
#pragma unroll
    for (int ni = 0; ni < 2; ++ni) {
        int col = col_base + w * 32 + ni * 16 + lm;
#pragma unroll
        for (int mi = 0; mi < 4; ++mi) {
            int rbase = row0 + mi * 16 + lq * 4;
#pragma unroll
            for (int r = 0; r < 4; ++r) {
                long idx = (long)(rbase + r) * H_SZ + col;
                if (PS) pz[idx] = acc[mi][ni][r];
                else    atomicAdd(&pz[idx], acc[mi][ni][r]);
            }
        }
    }
}

__global__ __launch_bounds__(512, 4) void k_gemm1_ps(
    const unsigned short* __restrict__ A, const unsigned short* __restrict__ Bt,
    float* __restrict__ p0, float* __restrict__ p1,
    float* __restrict__ p2, float* __restrict__ p3)
{ gemm1_body<1>(A, Bt, p0, p1, p2, p3); }

__global__ __launch_bounds__(512, 4) void k_gemm1_at(
    const unsigned short* __restrict__ A, const unsigned short* __restrict__ Bt,
    float* __restrict__ accbuf)
{ gemm1_body<0>(A, Bt, accbuf, accbuf, accbuf, accbuf); }

// ============ k_ep: partials -> relu(.+con1+b1) bf16 r1, + BN2 stats ========
// v2: grid 256 blocks x 16 rows (was 128 x 32) -> all CUs active.
template <int PS>
__device__ __forceinline__ void ep_body(
    const float* __restrict__ p0, const float* __restrict__ p1,
    const float* __restrict__ p2, const float* __restrict__ p3,
    const float* __restrict__ con1, const float* __restrict__ b1,
    unsigned short* __restrict__ r1, float* __restrict__ s2,
    float* __restrict__ s2q)
{
    __shared__ float con[H_SZ];
    int t = threadIdx.x, r0 = blockIdx.x * 16;
    con[t] = b1[t] + con1[t];
    con[t + 256] = b1[t + 256] + con1[t + 256];
    __syncthreads();
    float a0 = 0.f, q0 = 0.f, a1v = 0.f, q1 = 0.f;
    for (int r = 0; r < 16; ++r) {
        long base = (long)(r0 + r) * H_SZ;
        float v0, v1;
        if (PS) {
            v0 = p0[base + t] + p1[base + t] + p2[base + t] + p3[base + t]
               + con[t];
            v1 = p0[base + t + 256] + p1[base + t + 256]
               + p2[base + t + 256] + p3[base + t + 256] + con[t + 256];
        } else {
            v0 = p0[base + t] + con[t];
            v1 = p0[base + t + 256] + con[t + 256];
        }
        v0 = v0 > 0.f ? v0 : 0.f;
        v1 = v1 > 0.f ? v1 : 0.f;
        unsigned short h0 = f2b(v0), h1 = f2b(v1);
        r1[base + t] = h0; r1[base + t + 256] = h1;
        float b0 = b2f(h0), b1f = b2f(h1);
        a0 += b0; q0 += b0 * b0; a1v += b1f; q1 += b1f * b1f;
    }
    atomicAdd(&s2[t], a0);        atomicAdd(&s2q[t], q0);
    atomicAdd(&s2[t + 256], a1v); atomicAdd(&s2q[t + 256], q1);
}

__global__ __launch_bounds__(256) void k_ep_ps(
    const float* __restrict__ p0, const float* __restrict__ p1,
    const float* __restrict__ p2, const float* __restrict__ p3,
    const float* __restrict__ con1, const float* __restrict__ b1,
    unsigned short* __restrict__ r1, float* __restrict__ s2,
    float* __restrict__ s2q)
{ ep_body<1>(p0, p1, p2, p3, con1, b1, r1, s2, s2q); }

__global__ __launch_bounds__(256) void k_ep_at(
    const float* __restrict__ accbuf,
    const float* __restrict__ con1, const float* __restrict__ b1,
    unsigned short* __restrict__ r1, float* __restrict__ s2,
    float* __restrict__ s2q)
{ ep_body<0>(accbuf, accbuf, accbuf, accbuf, con1, b1, r1, s2, s2q); }

// ============ k_w2t: inline BN2 fold + W2^T bf16 cast + con2 ================
__global__ __launch_bounds__(256) void k_w2t(
    const float* __restrict__ W2, const float* __restrict__ s2,
    const float* __restrict__ s2q, const float* __restrict__ g2,
    const float* __restrict__ bb2, unsigned short* __restrict__ w2t,
    float* __restrict__ con)
{
    int gi = blockIdx.x * 256 + threadIdx.x;   // 64 kg * 512 n
    int kg = gi >> 9, n = gi & 511;
    short8 out; float cacc = 0.f;
#pragma unroll
    for (int i = 0; i < 8; ++i) {
        int k = kg * 8 + i;
        float m = s2[k] * (1.f / 4096.f);
        float var = s2q[k] * (1.f / 4096.f) - m * m;
        float av = g2[k] * rsqrtf(var + BN_EPS);
        float cv = bb2[k] - m * av;
        float w = W2[(long)k * H_SZ + n];
        out[i] = (short)f2b(av * w);
        cacc += cv * w;
    }
    *(short8*)(w2t + (long)n * H_SZ + kg * 8) = out;
    atomicAdd(&con[n], cacc);
}

// ====== k_gemm2: full-K bf16 MFMA, 2-phase dbuf, fused relu + col stats =====
__global__ __launch_bounds__(512) void k_gemm2(
    const unsigned short* __restrict__ A, const unsigned short* __restrict__ Bt,
    const float* __restrict__ cvec, const float* __restrict__ bvec,
    unsigned short* __restrict__ Out, float* __restrict__ ss,
    float* __restrict__ sq)
{
    const int Kp = H_SZ;
    __shared__ __align__(16) short As[2][128 * 32];   // 2 x 8 KB
    __shared__ __align__(16) short Bs[2][64 * 32];    // 2 x 4 KB
    const int t = threadIdx.x;
    const int w = t >> 6, l = t & 63;
    const int wm = w >> 1, wn = w & 1;
    const int lm = l & 15, lq = l >> 4;
    const int row0 = blockIdx.y * 128;
    const int col0 = blockIdx.x * 64;

    const unsigned short* gA = A + (long)(row0 + (t >> 2)) * Kp + ((t & 3) * 8);
    const unsigned short* gB = Bt + (long)(col0 + ((t >> 2) & 63)) * Kp + ((t & 3) * 8);

#define STAGE2(kt, pb) do {                                                   \
        gload_lds16(gA + (kt) * 32, &As[pb][w * 512]);                        \
        if (t < 256) gload_lds16(gB + (kt) * 32, &Bs[pb][w * 512]);           \
    } while (0)

    f32x4 acc00 = {0.f,0.f,0.f,0.f}, acc01 = acc00, acc10 = acc00, acc11 = acc00;

    STAGE2(0, 0);
    __syncthreads();

    for (int kt = 0; kt < Kp / 32; ++kt) {
        const int pb = kt & 1;
        if (kt < Kp / 32 - 1) STAGE2(kt + 1, pb ^ 1);   // prefetch FIRST
        const short* aBase0 = &As[pb][(wm * 32 + lm) * 32 + lq * 8];
        const short* bBase0 = &Bs[pb][(wn * 32 + lm) * 32 + lq * 8];
        short8 af0 = *(const short8*)aBase0;
        short8 af1 = *(const short8*)(aBase0 + 16 * 32);
        short8 bf0 = *(const short8*)bBase0;
        short8 bf1 = *(const short8*)(bBase0 + 16 * 32);
        acc00 = __builtin_amdgcn_mfma_f32_16x16x32_bf16(af0, bf0, acc00, 0, 0, 0);
        acc01 = __builtin_amdgcn_mfma_f32_16x16x32_bf16(af0, bf1, acc01, 0, 0, 0);
        acc10 = __builtin_amdgcn_mfma_f32_16x16x32_bf16(af1, bf0, acc10, 0, 0, 0);
        acc11 = __builtin_amdgcn_mfma_f32_16x16x32_bf16(af1, bf1, acc11, 0, 0, 0);
        __syncthreads();
    }
#undef STAGE2

    f32x4 accs[2][2] = {{acc00, acc01}, {acc10, acc11}};
#pragma unroll
    for (int ni = 0; ni < 2; ++ni) {
        int col = col0 + wn * 32 + ni * 16 + lm;
        float cb = cvec[col] + bvec[col];
        float psum = 0.f, psq = 0.f;
#pragma unroll
        for (int mi = 0; mi < 2; ++mi) {
            int rbase = row0 + wm * 32 + mi * 16 + lq * 4;
#pragma unroll
            for (int r = 0; r < 4; ++r) {
                float v = accs[mi][ni][r] + cb;
                v = v > 0.f ? v : 0.f;
                unsigned short h = f2b(v);
                Out[(long)(rbase + r) * H_SZ + col] = h;
                float vb = b2f(h);
                psum += vb; psq += vb * vb;
            }
        }
        psum += __shfl_xor(psum, 16, 64); psum += __shfl_xor(psum, 32, 64);
        psq  += __shfl_xor(psq , 16, 64); psq  += __shfl_xor(psq , 32, 64);
        if (lq == 0) { atomicAdd(&ss[col], psum); atomicAdd(&sq[col], psq); }
    }
}

// ============ k_final: inline BN3 fold + GEMV + lr ==========================
__global__ __launch_bounds__(256) void k_final(
    const unsigned short* __restrict__ r2, const float* __restrict__ s3,
    const float* __restrict__ s3q, const float* __restrict__ g3,
    const float* __restrict__ bb3, const float* __restrict__ w3s,
    const float* __restrict__ b3, const float* __restrict__ lr_score,
    float* __restrict__ out)
{
    int t = threadIdx.x, w = t >> 6, l = t & 63;
    int b = blockIdx.x * 4 + w;
    float acc = 0.f;
#pragma unroll
    for (int i = 0; i < 8; ++i) {
        int e = i * 64 + l;
        float m = s3[e] * (1.f / 4096.f);
        float var = s3q[e] * (1.f / 4096.f) - m * m;
        float a3 = g3[e] * rsqrtf(var + BN_EPS);
        float c3 = bb3[e] - m * a3;
        float v = a3 * b2f(r2[(long)b * H_SZ + e]) + c3;
        acc += v * w3s[e] + b3[e];
    }
    for (int s = 32; s; s >>= 1) acc += __shfl_down(acc, s, 64);
    if (l == 0) out[b] = lr_score[b] + acc;
}

// ---------------- launcher ----------------
extern "C" void kernel_launch(void* const* d_in, const int* in_sizes, int n_in,
                              void* d_out, int out_size, void* d_ws, size_t ws_size,
                              hipStream_t stream) {
    const int*   st_ids = (const int*)d_in[0];
    const int*   dy_ids = (const int*)d_in[1];
    const int*   dy_len = (const int*)d_in[2];
    const float* st_emb = (const float*)d_in[3];
    const float* dy_emb = (const float*)d_in[4];
    const float* st_lr  = (const float*)d_in[5];
    const float* dy_lr  = (const float*)d_in[6];
    const float* bias   = (const float*)d_in[7];
    const float* bn1_g  = (const float*)d_in[8];
    const float* bn1_b  = (const float*)d_in[9];
    const float* W1     = (const float*)d_in[10];
    const float* b1     = (const float*)d_in[11];
    const float* bn2_g  = (const float*)d_in[12];
    const float* bn2_b  = (const float*)d_in[13];
    const float* W2     = (const float*)d_in[14];
    const float* b2     = (const float*)d_in[15];
    const float* bn3_g  = (const float*)d_in[16];
    const float* bn3_b  = (const float*)d_in[17];
    const float* W3     = (const float*)d_in[18];
    const float* b3     = (const float*)d_in[19];
    // d_in[20..23] feed only the dead final layer — skipped.

    char* ws = (char*)d_ws;
    size_t off = 0;
    auto alloc = [&](size_t bytes) -> char* {
        char* p = ws + off;
        off = (off + bytes + 255) & ~(size_t)255;
        return p;
    };
    // Union region R (8.39 MB), time-multiplexed:
    //   phase 1: all_emb (7.87 MB)      [k_stemb..k_x]
    //   phase 2: accbuf / partial z=0   [k_gemm1 -> k_ep]
    //   phase 3: r2      (4.19 MB)      [k_gemm2 -> k_final]
    char* R = alloc((size_t)B_SZ * H_SZ * 4);      // 8,388,608 B
    float*          all_emb = (float*)R;
    float*          accbuf  = (float*)R;           // = partial z=0 in PS mode
    unsigned short* r2      = (unsigned short*)R;

    unsigned short* x16     = (unsigned short*)alloc((size_t)B_SZ * KP * 2);
    unsigned short* w1t     = (unsigned short*)alloc((size_t)H_SZ * KP * 2);
    unsigned short* r1      = (unsigned short*)alloc((size_t)B_SZ * H_SZ * 2);
    unsigned short* w2t     = (unsigned short*)alloc((size_t)H_SZ * H_SZ * 2);
    float*          lr_sc   = (float*)alloc(B_SZ * 4);
    float* a1  = (float*)alloc(KP * 4);
    float* c1  = (float*)alloc(KP * 4);
    float* w3s = (float*)alloc(H_SZ * 4);
    char* zstart = ws + off;                       // ---- zeroed stats ----
    float* s1   = (float*)alloc(KP * 4);
    float* s1q  = (float*)alloc(KP * 4);
    float* con1 = (float*)alloc(H_SZ * 4);
    float* s2   = (float*)alloc(H_SZ * 4);
    float* s2q  = (float*)alloc(H_SZ * 4);
    float* con2 = (float*)alloc(H_SZ * 4);
    float* s3   = (float*)alloc(H_SZ * 4);
    float* s3q  = (float*)alloc(H_SZ * 4);
    size_t zbytes = (size_t)((ws + off) - zstart);
    // base layout ≈ 79.3 MB (< 81.2 MB proven safe)

    // Optional split-K partial buffers (z=1..3); z=0 reuses R.  Only used if
    // the workspace is big enough — otherwise fall back to atomic path.
    float* pb1 = (float*)alloc((size_t)B_SZ * H_SZ * 4);
    float* pb2 = (float*)alloc((size_t)B_SZ * H_SZ * 4);
    float* pb3 = (float*)alloc((size_t)B_SZ * H_SZ * 4);
    const bool ps = (off <= ws_size);              // ~104.5 MB needed

    hipMemsetAsync(zstart, 0, zbytes, stream);
    k_stemb<<<(B_SZ * F_ST * 4) / 256, 256, 0, stream>>>(st_ids, st_emb, all_emb);
    k_dyemb<<<(B_SZ * F_DY) / 8, 512, 0, stream>>>(dy_ids, dy_len, dy_emb, all_emb);
    k_lr<<<B_SZ / 8, 512, 0, stream>>>(st_ids, dy_ids, dy_len, st_lr, dy_lr,
                                       bias, lr_sc);
    k_x<<<B_SZ / 16, 1024, 0, stream>>>(all_emb, x16, s1, s1q);
    k_prep<<<60, 256, 0, stream>>>(s1, s1q, bn1_g, bn1_b, a1, c1, W3, w3s);
    k_w1t<<<(896 * 512) / 256, 256, 0, stream>>>(W1, a1, c1, w1t, con1);
    if (ps) {
        // all_emb dead; R = partial z=0 (fully overwritten, no memset needed)
        k_gemm1_ps<<<512, 512, 0, stream>>>(x16, w1t, accbuf, pb1, pb2, pb3);
        k_ep_ps<<<256, 256, 0, stream>>>(accbuf, pb1, pb2, pb3, con1, b1,
                                         r1, s2, s2q);
    } else {
        hipMemsetAsync(R, 0, (size_t)B_SZ * H_SZ * 4, stream);
        k_gemm1_at<<<512, 512, 0, stream>>>(x16, w1t, accbuf);
        k_ep_at<<<256, 256, 0, stream>>>(accbuf, con1, b1, r1, s2, s2q);
    }
    k_w2t<<<128, 256, 0, stream>>>(W2, s2, s2q, bn2_g, bn2_b, w2t, con2);
    // accbuf dead; repurpose R as r2
    k_gemm2<<<dim3(8, 32), 512, 0, stream>>>(r1, w2t, con2, b2, r2, s3, s3q);
    k_final<<<B_SZ / 4, 256, 0, stream>>>(r2, s3, s3q, bn3_g, bn3_b, w3s, b3,
                                          lr_sc, (float*)d_out);
}